// Round 1
// baseline (116.111 us; speedup 1.0000x reference)
//
#include <hip/hip_runtime.h>

#define HH 384
#define WW 384
#define HWP (HH * WW)   // 147456
#define DD 64
#define BB 2

// K1: per-pixel channel stats: ssq = sum_d v^2, smm = sum_d v
__global__ __launch_bounds__(256) void stats_k(const float* __restrict__ des,
                                               float* __restrict__ ssq,
                                               float* __restrict__ smm) {
    int idx = blockIdx.x * 256 + threadIdx.x;        // 0 .. 294911
    int b = idx / HWP;
    int p = idx - b * HWP;
    const float* base = des + (size_t)b * DD * HWP + p;
    float ss = 0.f, s0 = 0.f;
#pragma unroll 8
    for (int d = 0; d < DD; ++d) {
        float v = base[(size_t)d * HWP];
        ss = fmaf(v, v, ss);
        s0 += v;
    }
    ssq[idx] = ss;
    smm[idx] = s0;
}

// K2: per-pixel dots with 25 dilated neighbors + epilogue
// block (64,4): lane-contiguous x for coalesced loads. 1 pixel per thread.
__global__ __launch_bounds__(256) void ssd_k(const float* __restrict__ des,
                                             const float* __restrict__ ssq,
                                             const float* __restrict__ smm,
                                             float* __restrict__ out) {
    const int x = blockIdx.x * 64 + threadIdx.x;
    const int y = blockIdx.y * 4 + threadIdx.y;
    const int b = blockIdx.z;

    int rowoff[5], coloff[5];
#pragma unroll
    for (int m = 0; m < 5; ++m) {
        int yy = y - 8 + 4 * m;
        yy = yy < 0 ? 0 : (yy > HH - 1 ? HH - 1 : yy);
        rowoff[m] = yy * WW;
    }
#pragma unroll
    for (int j = 0; j < 5; ++j) {
        int xx = x - 8 + 4 * j;
        xx = xx < 0 ? 0 : (xx > WW - 1 ? WW - 1 : xx);
        coloff[j] = xx;
    }

    float acc[25];
#pragma unroll
    for (int n = 0; n < 25; ++n) acc[n] = 0.f;

    const float* dp = des + (size_t)b * DD * HWP;
#pragma unroll 2
    for (int d = 0; d < DD; ++d) {
        float v[25];
#pragma unroll
        for (int m = 0; m < 5; ++m)
#pragma unroll
            for (int j = 0; j < 5; ++j)
                v[m * 5 + j] = dp[rowoff[m] + coloff[j]];
        float c = v[12];   // center (m=2,j=2) = offset (0,0)
#pragma unroll
        for (int n = 0; n < 25; ++n)
            acc[n] = fmaf(c, v[n], acc[n]);
        dp += HWP;
    }

    const float* sq = ssq + (size_t)b * HWP;
    const int cidx = y * WW + x;
    float ssA = sq[cidx];
    float mu = smm[(size_t)b * HWP + cidx] * (1.0f / 64);
    float var = ssA * (1.0f / 64) - mu * mu;
    float sabs = sqrtf(fmaxf(var, 0.f));

    float L = 0.f;
#pragma unroll
    for (int m = 0; m < 5; ++m)
#pragma unroll
        for (int j = 0; j < 5; ++j) {
            float ssB = sq[rowoff[m] + coloff[j]];
            float d2 = fmaxf(ssA + ssB - 2.f * acc[m * 5 + j], 0.f);
            L += sqrtf(d2);
        }
    float srel = L * (1.0f / 25);
    float sraw = sabs * srel;
    out[(size_t)b * HWP + cidx] = sraw / (sraw + 1.f);
}

extern "C" void kernel_launch(void* const* d_in, const int* in_sizes, int n_in,
                              void* d_out, int out_size, void* d_ws, size_t ws_size,
                              hipStream_t stream) {
    const float* des = (const float*)d_in[0];
    float* out = (float*)d_out;
    float* ssq = (float*)d_ws;                 // BB*HWP floats
    float* smm = ssq + (size_t)BB * HWP;       // BB*HWP floats

    stats_k<<<dim3((BB * HWP) / 256), dim3(256), 0, stream>>>(des, ssq, smm);
    ssd_k<<<dim3(WW / 64, HH / 4, BB), dim3(64, 4), 0, stream>>>(des, ssq, smm, out);
}

// Round 2
// 105.964 us; speedup vs baseline: 1.0958x; 1.0958x over previous
//
#include <hip/hip_runtime.h>

#define HH 384
#define WW 384
#define HWP (HH * WW)   // 147456
#define DD 64
#define BB 2

#define TX 64
#define TY 8
#define LR 24           // TY + 16 halo rows
#define LC 80           // TX + 16 halo cols
#define LN (LR * LC)    // 1920 floats per buffer
#define NBX (WW / TX)   // 6
#define NBY (HH / TY)   // 48
#define NWG (NBX * NBY * BB)  // 576 = 8 XCD * 72

// K1: per-pixel channel stats: ssq = sum_d v^2, smm = sum_d v
__global__ __launch_bounds__(256) void stats_k(const float* __restrict__ des,
                                               float* __restrict__ ssq,
                                               float* __restrict__ smm) {
    int idx = blockIdx.x * 256 + threadIdx.x;
    int b = idx / HWP;
    int p = idx - b * HWP;
    const float* base = des + (size_t)b * DD * HWP + p;
    float ss = 0.f, s0 = 0.f;
#pragma unroll 8
    for (int d = 0; d < DD; ++d) {
        float v = base[(size_t)d * HWP];
        ss = fmaf(v, v, ss);
        s0 += v;
    }
    ssq[idx] = ss;
    smm[idx] = s0;
}

// K2: LDS-staged dilated 5x5 dot-product stencil, 2 px/thread (y, y+4),
// double-buffered over channels.
__global__ __launch_bounds__(256) void ssd_k(const float* __restrict__ des,
                                             const float* __restrict__ ssq,
                                             const float* __restrict__ smm,
                                             float* __restrict__ out) {
    __shared__ float lds[2][LN];
    const int tx = threadIdx.x;            // 0..63
    const int ty = threadIdx.y;            // 0..3
    const int tid = ty * 64 + tx;

    // XCD-aware bijective swizzle: blocks bid%8==x -> XCD x get contiguous stripe
    int bid = blockIdx.x;
    int swz = (bid & 7) * (NWG / 8) + (bid >> 3);
    int b  = swz / (NBX * NBY);
    int r0 = swz % (NBX * NBY);
    int by = r0 / NBX;
    int bx = r0 - by * NBX;
    const int x0 = bx * TX, y0 = by * TY;

    // Precompute clamped global offsets for the 8 staging slots of this thread
    int goff[8];
#pragma unroll
    for (int k = 0; k < 8; ++k) {
        int i = tid + 256 * k;
        if (i < LN) {
            int r = i / LC, c = i - (i / LC) * LC;
            int gy = y0 + r - 8; gy = gy < 0 ? 0 : (gy > HH - 1 ? HH - 1 : gy);
            int gx = x0 + c - 8; gx = gx < 0 ? 0 : (gx > WW - 1 ? WW - 1 : gx);
            goff[k] = gy * WW + gx;
        } else {
            goff[k] = 0;   // inactive slot (k==7, tid>=128): harmless load
        }
    }

    const float* dp = des + (size_t)b * DD * HWP;
    float rg[8];

    auto LOADCH = [&](int ch) {
        const float* p = dp + (size_t)ch * HWP;
#pragma unroll
        for (int k = 0; k < 8; ++k) rg[k] = p[goff[k]];
    };
    auto WRITE = [&](int bb) {
#pragma unroll
        for (int k = 0; k < 7; ++k) lds[bb][tid + 256 * k] = rg[k];
        if (tid < LN - 1792) lds[bb][tid + 1792] = rg[7];
    };

    float acc[2][25];
#pragma unroll
    for (int a = 0; a < 2; ++a)
#pragma unroll
        for (int n = 0; n < 25; ++n) acc[a][n] = 0.f;

    auto COMPUTE = [&](int bb) {
        float v[6][5];
#pragma unroll
        for (int m = 0; m < 6; ++m)
#pragma unroll
            for (int j = 0; j < 5; ++j)
                v[m][j] = lds[bb][(ty + 4 * m) * LC + tx + 4 * j];
        float c0 = v[2][2];   // center of px (y0+ty)
        float c1 = v[3][2];   // center of px (y0+ty+4)
#pragma unroll
        for (int m = 0; m < 5; ++m)
#pragma unroll
            for (int j = 0; j < 5; ++j) {
                acc[0][m * 5 + j] = fmaf(c0, v[m][j],     acc[0][m * 5 + j]);
                acc[1][m * 5 + j] = fmaf(c1, v[m + 1][j], acc[1][m * 5 + j]);
            }
    };

    // prologue: stage channel 0
    LOADCH(0);
    WRITE(0);
    __syncthreads();

    for (int ch = 0; ch < DD; ch += 2) {
        LOADCH(ch + 1);
        COMPUTE(0);
        WRITE(1);
        __syncthreads();
        if (ch + 2 < DD) LOADCH(ch + 2);
        COMPUTE(1);
        if (ch + 2 < DD) WRITE(0);
        __syncthreads();
    }

    // epilogue: stage ssq tile into buffer 0
    const float* sp = ssq + (size_t)b * HWP;
#pragma unroll
    for (int k = 0; k < 8; ++k) rg[k] = sp[goff[k]];
    WRITE(0);
    __syncthreads();

    float sv[6][5];
#pragma unroll
    for (int m = 0; m < 6; ++m)
#pragma unroll
        for (int j = 0; j < 5; ++j)
            sv[m][j] = lds[0][(ty + 4 * m) * LC + tx + 4 * j];

#pragma unroll
    for (int a = 0; a < 2; ++a) {
        int py = ty + 4 * a;
        float ssA = sv[2 + a][2];
        float mu = smm[(size_t)b * HWP + (y0 + py) * WW + x0 + tx] * (1.0f / 64);
        float var = ssA * (1.0f / 64) - mu * mu;
        float sabs = sqrtf(fmaxf(var, 0.f));
        float L = 0.f;
#pragma unroll
        for (int m = 0; m < 5; ++m)
#pragma unroll
            for (int j = 0; j < 5; ++j) {
                float ssB = sv[m + a][j];
                float d2 = fmaxf(ssA + ssB - 2.f * acc[a][m * 5 + j], 0.f);
                L += sqrtf(d2);
            }
        float srel = L * (1.0f / 25);
        float sraw = sabs * srel;
        out[(size_t)b * HWP + (y0 + py) * WW + x0 + tx] = sraw / (sraw + 1.f);
    }
}

extern "C" void kernel_launch(void* const* d_in, const int* in_sizes, int n_in,
                              void* d_out, int out_size, void* d_ws, size_t ws_size,
                              hipStream_t stream) {
    const float* des = (const float*)d_in[0];
    float* out = (float*)d_out;
    float* ssq = (float*)d_ws;
    float* smm = ssq + (size_t)BB * HWP;

    stats_k<<<dim3((BB * HWP) / 256), dim3(256), 0, stream>>>(des, ssq, smm);
    ssd_k<<<dim3(NWG), dim3(64, 4), 0, stream>>>(des, ssq, smm, out);
}

// Round 3
// 95.403 us; speedup vs baseline: 1.2171x; 1.1107x over previous
//
#include <hip/hip_runtime.h>

#define HH 384
#define WW 384
#define HWP (HH * WW)   // 147456
#define DD 64
#define BB 2

#define TX 64
#define TY 8
#define LR 24           // TY + 16 halo rows
#define LC 80           // TX + 16 halo cols
#define LN (LR * LC)    // 1920 slots per buffer
#define NBX (WW / TX)   // 6
#define NBY (HH / TY)   // 48
#define NWG (NBX * NBY * BB)  // 576 = 8 XCD * 72

// K1: per-pixel channel stats: ssq = sum_d v^2, smm = sum_d v
__global__ __launch_bounds__(256) void stats_k(const float* __restrict__ des,
                                               float* __restrict__ ssq,
                                               float* __restrict__ smm) {
    int idx = blockIdx.x * 256 + threadIdx.x;
    int b = idx / HWP;
    int p = idx - b * HWP;
    const float* base = des + (size_t)b * DD * HWP + p;
    float ss = 0.f, s0 = 0.f;
#pragma unroll 8
    for (int d = 0; d < DD; ++d) {
        float v = base[(size_t)d * HWP];
        ss = fmaf(v, v, ss);
        s0 += v;
    }
    ssq[idx] = ss;
    smm[idx] = s0;
}

// K2: LDS-staged dilated 5x5 dot stencil. Channel-innermost float4 LDS slots:
// each tap is one ds_read_b128 covering 4 channels. 2 px/thread (y, y+4).
__global__ __launch_bounds__(256) void ssd_k(const float* __restrict__ des,
                                             const float* __restrict__ ssq,
                                             const float* __restrict__ smm,
                                             float* __restrict__ out) {
    __shared__ float4 lds[2][LN];   // 61,440 B
    const int tx = threadIdx.x;            // 0..63
    const int ty = threadIdx.y;            // 0..3
    const int tid = ty * 64 + tx;

    // XCD-aware bijective swizzle (576 = 8 * 72)
    int bid = blockIdx.x;
    int swz = (bid & 7) * (NWG / 8) + (bid >> 3);
    int b  = swz / (NBX * NBY);
    int r0 = swz % (NBX * NBY);
    int by = r0 / NBX;
    int bx = r0 - by * NBX;
    const int x0 = bx * TX, y0 = by * TY;

    // Clamped global offsets for this thread's 8 staging slots
    int goff[8];
#pragma unroll
    for (int k = 0; k < 8; ++k) {
        int i = tid + 256 * k;
        if (i < LN) {
            int r = i / LC, c = i - (i / LC) * LC;
            int gy = y0 + r - 8; gy = gy < 0 ? 0 : (gy > HH - 1 ? HH - 1 : gy);
            int gx = x0 + c - 8; gx = gx < 0 ? 0 : (gx > WW - 1 ? WW - 1 : gx);
            goff[k] = gy * WW + gx;
        } else {
            goff[k] = 0;
        }
    }

    const float* dp = des + (size_t)b * DD * HWP;
    float4 rg[8];

    auto LOADG = [&](int g) {   // stage channels 4g..4g+3
        const float* p = dp + (size_t)(4 * g) * HWP;
#pragma unroll
        for (int k = 0; k < 8; ++k) {
            rg[k].x = p[goff[k]];
            rg[k].y = p[goff[k] + HWP];
            rg[k].z = p[goff[k] + 2 * HWP];
            rg[k].w = p[goff[k] + 3 * HWP];
        }
    };
    auto WRITE = [&](int bb) {
#pragma unroll
        for (int k = 0; k < 7; ++k) lds[bb][tid + 256 * k] = rg[k];
        if (tid < LN - 1792) lds[bb][tid + 1792] = rg[7];
    };

    float acc0[25], acc1[25];
#pragma unroll
    for (int n = 0; n < 25; ++n) { acc0[n] = 0.f; acc1[n] = 0.f; }

    auto COMPUTE = [&](int bb) {
        const float4* L = lds[bb];
        const int base = ty * LC + tx;
        float4 c0 = L[base + 8 * LC + 8];    // center of px y0+ty   (m=2,j=2)
        float4 c1 = L[base + 12 * LC + 8];   // center of px y0+ty+4 (m=3,j=2)
#pragma unroll
        for (int m = 0; m < 6; ++m) {
#pragma unroll
            for (int j = 0; j < 5; ++j) {
                float4 v = L[base + (4 * m) * LC + 4 * j];
                if (m < 5) {
                    int n = m * 5 + j;
                    acc0[n] = fmaf(c0.x, v.x, acc0[n]);
                    acc0[n] = fmaf(c0.y, v.y, acc0[n]);
                    acc0[n] = fmaf(c0.z, v.z, acc0[n]);
                    acc0[n] = fmaf(c0.w, v.w, acc0[n]);
                }
                if (m >= 1) {
                    int n = (m - 1) * 5 + j;
                    acc1[n] = fmaf(c1.x, v.x, acc1[n]);
                    acc1[n] = fmaf(c1.y, v.y, acc1[n]);
                    acc1[n] = fmaf(c1.z, v.z, acc1[n]);
                    acc1[n] = fmaf(c1.w, v.w, acc1[n]);
                }
            }
        }
    };

    // 16 channel-groups, double-buffered
    LOADG(0);
    WRITE(0);
    __syncthreads();
    for (int g = 0; g < 16; g += 2) {
        LOADG(g + 1);
        COMPUTE(0);
        WRITE(1);
        __syncthreads();
        if (g + 2 < 16) LOADG(g + 2);
        COMPUTE(1);
        if (g + 2 < 16) WRITE(0);
        __syncthreads();
    }

    // epilogue: stage ssq tile (scalar floats) into buffer 0
    float* lf = (float*)&lds[0][0];
    const float* sp = ssq + (size_t)b * HWP;
    {
        float r[8];
#pragma unroll
        for (int k = 0; k < 8; ++k) r[k] = sp[goff[k]];
#pragma unroll
        for (int k = 0; k < 7; ++k) lf[tid + 256 * k] = r[k];
        if (tid < LN - 1792) lf[tid + 1792] = r[7];
    }
    __syncthreads();

    float sv[6][5];
#pragma unroll
    for (int m = 0; m < 6; ++m)
#pragma unroll
        for (int j = 0; j < 5; ++j)
            sv[m][j] = lf[(ty + 4 * m) * LC + tx + 4 * j];

#pragma unroll
    for (int a = 0; a < 2; ++a) {
        int py = ty + 4 * a;
        float* acc = a ? acc1 : acc0;
        float ssA = sv[2 + a][2];
        float mu = smm[(size_t)b * HWP + (y0 + py) * WW + x0 + tx] * (1.0f / 64);
        float var = ssA * (1.0f / 64) - mu * mu;
        float sabs = sqrtf(fmaxf(var, 0.f));
        float L = 0.f;
#pragma unroll
        for (int m = 0; m < 5; ++m)
#pragma unroll
            for (int j = 0; j < 5; ++j) {
                float ssB = sv[m + a][j];
                float d2 = fmaxf(ssA + ssB - 2.f * acc[m * 5 + j], 0.f);
                L += sqrtf(d2);
            }
        float srel = L * (1.0f / 25);
        float sraw = sabs * srel;
        out[(size_t)b * HWP + (y0 + py) * WW + x0 + tx] = sraw / (sraw + 1.f);
    }
}

extern "C" void kernel_launch(void* const* d_in, const int* in_sizes, int n_in,
                              void* d_out, int out_size, void* d_ws, size_t ws_size,
                              hipStream_t stream) {
    const float* des = (const float*)d_in[0];
    float* out = (float*)d_out;
    float* ssq = (float*)d_ws;
    float* smm = ssq + (size_t)BB * HWP;

    stats_k<<<dim3((BB * HWP) / 256), dim3(256), 0, stream>>>(des, ssq, smm);
    ssd_k<<<dim3(NWG), dim3(64, 4), 0, stream>>>(des, ssq, smm, out);
}